// Round 14
// baseline (184.438 us; speedup 1.0000x reference)
//
#include <hip/hip_runtime.h>

#define NB 8192
#define NT 365
#define NF 5
#define NH 10
#define NG 40   // 4*NH
#define GPW 6   // 10-lane groups per wave (lanes 60..63 dead)

// One lane owns ONE hidden unit u (its 4 gate columns f,i,o,g; c[u]; h[u]).
// Cross-lane traffic: 10 ds_bpermute per step to broadcast the group's h.
// g-gate weights/bias pre-scaled x2 (tanh(x) = 2*sigmoid(2x)-1).
// x is prefetched in 8-step chunks of 10 float4 into a register double
// buffer (A/B) -- r13, kept.
//
// NEW vs r13: weights live in LDS, transposed per-unit: wlds4[u*17 + s],
// s=0..4 W_ih row f (gates in xyzw), s=5..14 W_hh row j, s=15 bias.
// 17-float4 stride (272B) puts lane u on banks 4u -> worst 2-way (free);
// the 6 groups read identical addresses (broadcast, free). Per step the
// 64 per-lane weight values are 16 ds_read_b128 instead of 64 global
// loads -- the r7..r13 counters showed the compiler NEVER keeps them in
// VGPRs (VGPR_Count 56..96 < weight count every round).
__global__ __launch_bounds__(256, 1)
void lstm_unit_lds(const float* __restrict__ x,
                   const float* __restrict__ w_ih,
                   const float* __restrict__ w_hh,
                   const float* __restrict__ bias,
                   const float* __restrict__ fc_w,
                   const float* __restrict__ fc_b,
                   float* __restrict__ out)
{
    __shared__ float4 wlds4[10 * 17];

    // ---- cooperative weight staging (once) ----
    {
        const int i = threadIdx.x;
        if (i < 170) {
            const int u = i / 17, s = i % 17;
            float4 v = make_float4(0.f, 0.f, 0.f, 0.f);
            if (s < 5) {                     // W_ih row f=s, gates q=0..3
                v.x = w_ih[s * NG + 0 * NH + u];
                v.y = w_ih[s * NG + 1 * NH + u];
                v.z = w_ih[s * NG + 2 * NH + u];
                v.w = w_ih[s * NG + 3 * NH + u] * 2.0f;
            } else if (s < 15) {             // W_hh row j=s-5
                const int j = s - 5;
                v.x = w_hh[j * NG + 0 * NH + u];
                v.y = w_hh[j * NG + 1 * NH + u];
                v.z = w_hh[j * NG + 2 * NH + u];
                v.w = w_hh[j * NG + 3 * NH + u] * 2.0f;
            } else if (s == 15) {            // bias
                v.x = bias[0 * NH + u];
                v.y = bias[1 * NH + u];
                v.z = bias[2 * NH + u];
                v.w = bias[3 * NH + u] * 2.0f;
            }                                 // s==16: pad
            wlds4[i] = v;
        }
        __syncthreads();
    }

    const int lane = threadIdx.x & 63;
    const int wid  = (blockIdx.x * 256 + threadIdx.x) >> 6;  // global wave id
    const int g    = lane / NH;          // group in wave (0..5; 6 => dead)
    const int u    = lane % NH;          // owned hidden unit
    const long b0  = (long)wid * GPW + g;
    const bool alive = (g < GPW) && (b0 < NB);
    const long b   = alive ? b0 : 0;     // clamped for safe addressing

    float* h_out = out + NB;
    float* c_out = h_out + (size_t)NB * NT * NH;

    const float4* wu = &wlds4[u * 17];   // this lane's weight block

    // bpermute byte-addresses of the 10 group members
    int aj[NH];
    #pragma unroll
    for (int j = 0; j < NH; ++j) aj[j] = (g * NH + j) * 4;

    float hAll[NH];
    #pragma unroll
    for (int j = 0; j < NH; ++j) hAll[j] = 0.f;
    float c = 0.f;

    const float* xp = x + (size_t)b * NT * NF;
    float* hcp = h_out + (size_t)b * NT * NH + u;
    float* ccp = c_out + (size_t)b * NT * NH + u;

    float A[40], B[40];   // x double-buffer: 8 steps x 5 features each

// load one 8-step chunk (40 contiguous floats, 10 float4)
#define LD8(dst, t0) { \
    const float4* p4 = reinterpret_cast<const float4*>(xp + (size_t)(t0) * NF); \
    _Pragma("unroll") \
    for (int i = 0; i < 10; ++i) { \
        float4 v = p4[i]; \
        dst[i*4+0] = v.x; dst[i*4+1] = v.y; dst[i*4+2] = v.z; dst[i*4+3] = v.w; } }

// tail: 5 steps = 25 floats (6 float4 + 1 dword), exactly to end of row
#define LDT(dst) { \
    const float4* p4 = reinterpret_cast<const float4*>(xp + (size_t)360 * NF); \
    _Pragma("unroll") \
    for (int i = 0; i < 6; ++i) { \
        float4 v = p4[i]; \
        dst[i*4+0] = v.x; dst[i*4+1] = v.y; dst[i*4+2] = v.z; dst[i*4+3] = v.w; } \
    dst[24] = xp[360 * NF + 24]; }

// one LSTM step; s is a literal -> all buf indices compile-time constants.
// Weight/bias reads are 16 ds_read_b128 from wu[] each step.
#define STEP(buf, s) { \
    const float4 bb = wu[15]; \
    float r0 = bb.x, r1 = bb.y, r2 = bb.z, r3 = bb.w; \
    _Pragma("unroll") \
    for (int f = 0; f < NF; ++f) { \
        const float4 wv = wu[f]; \
        const float xv = buf[(s) * NF + f]; \
        r0 = fmaf(xv, wv.x, r0); r1 = fmaf(xv, wv.y, r1); \
        r2 = fmaf(xv, wv.z, r2); r3 = fmaf(xv, wv.w, r3); } \
    _Pragma("unroll") \
    for (int j = 0; j < NH; ++j) { \
        const float4 wh = wu[5 + j]; \
        const float hv = hAll[j]; \
        r0 = fmaf(hv, wh.x, r0); r1 = fmaf(hv, wh.y, r1); \
        r2 = fmaf(hv, wh.z, r2); r3 = fmaf(hv, wh.w, r3); } \
    const float sf = __builtin_amdgcn_rcpf(1.0f + __expf(-r0)); \
    const float si = __builtin_amdgcn_rcpf(1.0f + __expf(-r1)); \
    const float so = __builtin_amdgcn_rcpf(1.0f + __expf(-r2)); \
    const float tg = fmaf(2.0f, __builtin_amdgcn_rcpf(1.0f + __expf(-r3)), -1.0f); \
    c = fmaf(sf, c, si * tg); \
    const float th = fmaf(2.0f, __builtin_amdgcn_rcpf(1.0f + __expf(-2.0f * c)), -1.0f); \
    const float h = so * th; \
    _Pragma("unroll") \
    for (int j = 0; j < NH; ++j) \
        hAll[j] = __int_as_float(__builtin_amdgcn_ds_bpermute(aj[j], __float_as_int(h))); \
    if (alive) { hcp[(s) * NH] = h; ccp[(s) * NH] = c; } }

#define RUN8(buf) { STEP(buf,0) STEP(buf,1) STEP(buf,2) STEP(buf,3) \
                    STEP(buf,4) STEP(buf,5) STEP(buf,6) STEP(buf,7) \
                    hcp += 8 * NH; ccp += 8 * NH; }

    LD8(A, 0)
    // 44 full chunks in 22 statically ping-ponged pairs: t = 0..351
    for (int cc = 0; cc < 22; ++cc) {
        const int t0 = cc * 16;
        LD8(B, t0 + 8)      // prefetch next chunk, then run current
        RUN8(A)
        LD8(A, t0 + 16)     // cc=21 -> t=352..359, in-bounds
        RUN8(B)
    }
    // A holds chunk t=352..359; prefetch tail, run, then 5 tail steps
    LDT(B)
    RUN8(A)
    { STEP(B,0) STEP(B,1) STEP(B,2) STEP(B,3) STEP(B,4) }   // t=360..364

    // ---- fc head: lane u==0 of each live group has hAll = h_{T-1} ----
    if (alive && u == 0) {
        float acc = fc_b[0];
        #pragma unroll
        for (int j = 0; j < NH; ++j) acc = fmaf(hAll[j], fc_w[j], acc);
        out[b] = acc;
    }
}

extern "C" void kernel_launch(void* const* d_in, const int* in_sizes, int n_in,
                              void* d_out, int out_size, void* d_ws, size_t ws_size,
                              hipStream_t stream) {
    const float* x    = (const float*)d_in[0];
    const float* wih  = (const float*)d_in[1];
    const float* whh  = (const float*)d_in[2];
    const float* bias = (const float*)d_in[3];
    const float* fcw  = (const float*)d_in[4];
    const float* fcb  = (const float*)d_in[5];
    float* out = (float*)d_out;

    const int nwave  = (NB + GPW - 1) / GPW;          // 1366 waves of work
    const int blocks = (nwave * 64 + 255) / 256;      // 342 blocks
    lstm_unit_lds<<<blocks, 256, 0, stream>>>(x, wih, whh, bias, fcw, fcb, out);
}

// Round 16
// 171.071 us; speedup vs baseline: 1.0781x; 1.0781x over previous
//
#include <hip/hip_runtime.h>

#define NB 8192
#define NT 365
#define NF 5
#define NH 10
#define NG 40   // 4*NH
#define GPW 6   // 10-lane groups per wave (lanes 60..63 dead)

// One lane owns ONE hidden unit u (its 4 gate columns f,i,o,g; c[u]; h[u]).
// Cross-lane traffic: 10 ds_bpermute per step to broadcast the group's h.
// g-gate weights/bias pre-scaled x2 (tanh(x) = 2*sigmoid(2x)-1).
// x prefetched in 8-step chunks of 10 float4 into a register double buffer
// (A/B) -- r13, kept (the win: 275->175us).
//
// NEW vs r13: per-chunk "weight refresh" -- every outer iteration each of
// the 68 weight scalars passes through an opaque volatile v_xor_b32 with an
// asm-produced zero SGPR. This makes the weights LOOP-WRITTEN values (like
// the A/B buffers the allocator demonstrably keeps resident) instead of
// loop-invariant load results (which r7-r14 counters prove it re-fetches
// every step: VGPR_Count 56..124 < live-value count in every round).
__global__ __launch_bounds__(256, 1)
void lstm_unit_xw(const float* __restrict__ x,
                  const float* __restrict__ w_ih,
                  const float* __restrict__ w_hh,
                  const float* __restrict__ bias,
                  const float* __restrict__ fc_w,
                  const float* __restrict__ fc_b,
                  float* __restrict__ out)
{
    const int lane = threadIdx.x & 63;
    const int wid  = (blockIdx.x * 256 + threadIdx.x) >> 6;  // global wave id
    const int g    = lane / NH;          // group in wave (0..5; 6 => dead)
    const int u    = lane % NH;          // owned hidden unit
    const long b0  = (long)wid * GPW + g;
    const bool alive = (g < GPW) && (b0 < NB);
    const long b   = alive ? b0 : 0;     // clamped for safe addressing

    float* h_out = out + NB;
    float* c_out = h_out + (size_t)NB * NT * NH;

    // ---- per-lane weights: 4 columns x (5 ih + 10 hh) + 4 bias ----
    float wih[NF][4], whh[NH][4], bq[4];
    #pragma unroll
    for (int q = 0; q < 4; ++q) {
        const float gs = (q == 3) ? 2.0f : 1.0f;
        const int col = q * NH + u;
        #pragma unroll
        for (int f = 0; f < NF; ++f) wih[f][q] = w_ih[f * NG + col] * gs;
        #pragma unroll
        for (int j = 0; j < NH; ++j) whh[j][q] = w_hh[j * NG + col] * gs;
        bq[q] = bias[col] * gs;
    }

    // opaque zero (SGPR); the compiler cannot prove it is zero
    int zo;
    asm volatile("s_mov_b32 %0, 0" : "=s"(zo));
// volatile xor: cannot be DCE'd, duplicated, or rematerialized ->
// the weight becomes a loop-carried register value.
#define RW(v) asm volatile("v_xor_b32 %0, %1, %0" : "+v"(v) : "s"(zo));
#define REFRESH { \
    _Pragma("unroll") \
    for (int q = 0; q < 4; ++q) { \
        RW(bq[q]) \
        _Pragma("unroll") \
        for (int f = 0; f < NF; ++f) RW(wih[f][q]) \
        _Pragma("unroll") \
        for (int j = 0; j < NH; ++j) RW(whh[j][q]) } }

    // bpermute byte-addresses of the 10 group members
    int aj[NH];
    #pragma unroll
    for (int j = 0; j < NH; ++j) aj[j] = (g * NH + j) * 4;

    float hAll[NH];
    #pragma unroll
    for (int j = 0; j < NH; ++j) hAll[j] = 0.f;
    float c = 0.f;

    const float* xp = x + (size_t)b * NT * NF;
    float* hcp = h_out + (size_t)b * NT * NH + u;
    float* ccp = c_out + (size_t)b * NT * NH + u;

    float A[40], B[40];   // x double-buffer: 8 steps x 5 features each

// load one 8-step chunk (40 contiguous floats, 10 float4)
#define LD8(dst, t0) { \
    const float4* p4 = reinterpret_cast<const float4*>(xp + (size_t)(t0) * NF); \
    _Pragma("unroll") \
    for (int i = 0; i < 10; ++i) { \
        float4 v = p4[i]; \
        dst[i*4+0] = v.x; dst[i*4+1] = v.y; dst[i*4+2] = v.z; dst[i*4+3] = v.w; } }

// tail: 5 steps = 25 floats (6 float4 + 1 dword), exactly to end of row
#define LDT(dst) { \
    const float4* p4 = reinterpret_cast<const float4*>(xp + (size_t)360 * NF); \
    _Pragma("unroll") \
    for (int i = 0; i < 6; ++i) { \
        float4 v = p4[i]; \
        dst[i*4+0] = v.x; dst[i*4+1] = v.y; dst[i*4+2] = v.z; dst[i*4+3] = v.w; } \
    dst[24] = xp[360 * NF + 24]; }

// one LSTM step; s is a literal -> all buf indices compile-time constants
#define STEP(buf, s) { \
    float r0 = bq[0], r1 = bq[1], r2 = bq[2], r3 = bq[3]; \
    _Pragma("unroll") \
    for (int f = 0; f < NF; ++f) { \
        const float xv = buf[(s) * NF + f]; \
        r0 = fmaf(xv, wih[f][0], r0); r1 = fmaf(xv, wih[f][1], r1); \
        r2 = fmaf(xv, wih[f][2], r2); r3 = fmaf(xv, wih[f][3], r3); } \
    _Pragma("unroll") \
    for (int j = 0; j < NH; ++j) { \
        const float hv = hAll[j]; \
        r0 = fmaf(hv, whh[j][0], r0); r1 = fmaf(hv, whh[j][1], r1); \
        r2 = fmaf(hv, whh[j][2], r2); r3 = fmaf(hv, whh[j][3], r3); } \
    const float sf = __builtin_amdgcn_rcpf(1.0f + __expf(-r0)); \
    const float si = __builtin_amdgcn_rcpf(1.0f + __expf(-r1)); \
    const float so = __builtin_amdgcn_rcpf(1.0f + __expf(-r2)); \
    const float tg = fmaf(2.0f, __builtin_amdgcn_rcpf(1.0f + __expf(-r3)), -1.0f); \
    c = fmaf(sf, c, si * tg); \
    const float th = fmaf(2.0f, __builtin_amdgcn_rcpf(1.0f + __expf(-2.0f * c)), -1.0f); \
    const float h = so * th; \
    _Pragma("unroll") \
    for (int j = 0; j < NH; ++j) \
        hAll[j] = __int_as_float(__builtin_amdgcn_ds_bpermute(aj[j], __float_as_int(h))); \
    if (alive) { hcp[(s) * NH] = h; ccp[(s) * NH] = c; } }

#define RUN8(buf) { STEP(buf,0) STEP(buf,1) STEP(buf,2) STEP(buf,3) \
                    STEP(buf,4) STEP(buf,5) STEP(buf,6) STEP(buf,7) \
                    hcp += 8 * NH; ccp += 8 * NH; }

    LD8(A, 0)
    // 44 full chunks in 22 statically ping-ponged pairs: t = 0..351
    for (int cc = 0; cc < 22; ++cc) {
        REFRESH                    // weights become loop-carried register values
        const int t0 = cc * 16;
        LD8(B, t0 + 8)             // prefetch next chunk, then run current
        RUN8(A)
        LD8(A, t0 + 16)            // cc=21 -> t=352..359, in-bounds
        RUN8(B)
    }
    // A holds chunk t=352..359; prefetch tail, run, then 5 tail steps
    LDT(B)
    RUN8(A)
    { STEP(B,0) STEP(B,1) STEP(B,2) STEP(B,3) STEP(B,4) }   // t=360..364

    // ---- fc head: lane u==0 of each live group has hAll = h_{T-1} ----
    if (alive && u == 0) {
        float acc = fc_b[0];
        #pragma unroll
        for (int j = 0; j < NH; ++j) acc = fmaf(hAll[j], fc_w[j], acc);
        out[b] = acc;
    }
}

extern "C" void kernel_launch(void* const* d_in, const int* in_sizes, int n_in,
                              void* d_out, int out_size, void* d_ws, size_t ws_size,
                              hipStream_t stream) {
    const float* x    = (const float*)d_in[0];
    const float* wih  = (const float*)d_in[1];
    const float* whh  = (const float*)d_in[2];
    const float* bias = (const float*)d_in[3];
    const float* fcw  = (const float*)d_in[4];
    const float* fcb  = (const float*)d_in[5];
    float* out = (float*)d_out;

    const int nwave  = (NB + GPW - 1) / GPW;          // 1366 waves of work
    const int blocks = (nwave * 64 + 255) / 256;      // 342 blocks
    lstm_unit_xw<<<blocks, 256, 0, stream>>>(x, wih, whh, bias, fcw, fcb, out);
}